// Round 1
// baseline (861.920 us; speedup 1.0000x reference)
//
#include <hip/hip_runtime.h>

#define IN_SIZE 256
#define OUT_SIZE 64

// ---------------------------------------------------------------------------
// Stage 1: degree count (non-self edges). deg pre-zeroed by memsetAsync.
__global__ __launch_bounds__(256) void deg_kernel(const int* __restrict__ row,
                                                  const int* __restrict__ col,
                                                  float* __restrict__ deg,
                                                  int n_edges) {
  int e = blockIdx.x * 256 + threadIdx.x;
  if (e < n_edges) {
    int r = row[e], c = col[e];
    if (r != c) atomicAdd(&deg[r], 1.0f);
  }
}

// Stage 2: dinv = (deg + 1)^-1/2   (the +1 is the added self-loop; deg+1 >= 1
// always, so the deg>0 guard in the reference is vacuous).
__global__ __launch_bounds__(256) void dinv_kernel(const float* __restrict__ deg,
                                                   float* __restrict__ dinv,
                                                   int n_nodes) {
  int i = blockIdx.x * 256 + threadIdx.x;
  if (i < n_nodes) dinv[i] = rsqrtf(deg[i] + 1.0f);
}

// ---------------------------------------------------------------------------
// Stage 3: xw = x @ W.T   [N,256] x [64,256]^T -> [N,64], fp32.
// Block = 256 threads handles 64 nodes. Thread (og, ng): outputs og*4..og*4+3
// for nodes nbase+ng*4 .. +3. 4x4 register tile -> 16 acc, float4 k-steps.
// W (64 KB) is read straight from global: all blocks share it -> L2 broadcast.
__global__ __launch_bounds__(256) void matmul_kernel(const float* __restrict__ x,
                                                     const float* __restrict__ W,
                                                     float* __restrict__ xw,
                                                     int n_nodes) {
  int tid = threadIdx.x;
  int og = tid & 15;   // output group: cols og*4 .. og*4+3
  int ng = tid >> 4;   // node group 0..15
  long nbase = (long)blockIdx.x * 64 + (long)ng * 4;

  float acc[4][4];  // [out][node]
#pragma unroll
  for (int i = 0; i < 4; i++)
#pragma unroll
    for (int j = 0; j < 4; j++) acc[i][j] = 0.0f;

  for (int k = 0; k < IN_SIZE; k += 4) {
    float4 wv[4];
#pragma unroll
    for (int i = 0; i < 4; i++)
      wv[i] = *(const float4*)(W + (size_t)(og * 4 + i) * IN_SIZE + k);
#pragma unroll
    for (int j = 0; j < 4; j++) {
      long n = nbase + j;
      float4 xv = (n < n_nodes) ? *(const float4*)(x + n * IN_SIZE + k)
                                : make_float4(0.f, 0.f, 0.f, 0.f);
#pragma unroll
      for (int i = 0; i < 4; i++) {
        acc[i][j] += wv[i].x * xv.x + wv[i].y * xv.y + wv[i].z * xv.z +
                     wv[i].w * xv.w;
      }
    }
  }

#pragma unroll
  for (int j = 0; j < 4; j++) {
    long n = nbase + j;
    if (n < n_nodes) {
#pragma unroll
      for (int i = 0; i < 4; i++)
        xw[n * OUT_SIZE + og * 4 + i] = acc[i][j];
    }
  }
}

// ---------------------------------------------------------------------------
// Stage 4: out = dinv^2 * xw  (the self-loop term; also initializes out, so
// no separate memset of d_out is needed).
__global__ __launch_bounds__(256) void self_kernel(const float* __restrict__ dinv,
                                                   const float* __restrict__ xw,
                                                   float* __restrict__ out,
                                                   long total) {
  long i = (long)blockIdx.x * 256 + threadIdx.x;
  if (i < total) {
    int node = (int)(i >> 6);
    float d = dinv[node];
    out[i] = d * d * xw[i];
  }
}

// ---------------------------------------------------------------------------
// Stage 5: edge scatter. One thread per (edge, channel).
// out[r,ch] += dinv[r]*dinv[c] * xw[c,ch]  for r != c.
__global__ __launch_bounds__(256) void scatter_kernel(const int* __restrict__ row,
                                                      const int* __restrict__ col,
                                                      const float* __restrict__ dinv,
                                                      const float* __restrict__ xw,
                                                      float* __restrict__ out,
                                                      int n_edges) {
  long gid = (long)blockIdx.x * 256 + threadIdx.x;
  long e = gid >> 6;
  int ch = (int)(gid & 63);
  if (e >= n_edges) return;
  int r = row[e];
  int c = col[e];
  if (r == c) return;
  float w = dinv[r] * dinv[c];
  atomicAdd(&out[(long)r * OUT_SIZE + ch], w * xw[(long)c * OUT_SIZE + ch]);
}

// ---------------------------------------------------------------------------
extern "C" void kernel_launch(void* const* d_in, const int* in_sizes, int n_in,
                              void* d_out, int out_size, void* d_ws,
                              size_t ws_size, hipStream_t stream) {
  const int* edge_index = (const int*)d_in[0];
  const float* x = (const float*)d_in[1];
  const float* W = (const float*)d_in[3];

  int n_edges = in_sizes[0] / 2;
  int n_nodes = in_sizes[1] / IN_SIZE;
  const int* row = edge_index;
  const int* col = edge_index + n_edges;
  float* out = (float*)d_out;

  // Workspace layout: deg [N f32] | dinv [N f32] | xw [N*64 f32]
  char* ws = (char*)d_ws;
  float* deg = (float*)ws;
  float* dinv = (float*)(ws + (size_t)n_nodes * 4);
  float* xw = (float*)(ws + (size_t)n_nodes * 8);  // 800000 B offset, 16B aligned

  hipMemsetAsync(deg, 0, (size_t)n_nodes * 4, stream);

  deg_kernel<<<(n_edges + 255) / 256, 256, 0, stream>>>(row, col, deg, n_edges);
  dinv_kernel<<<(n_nodes + 255) / 256, 256, 0, stream>>>(deg, dinv, n_nodes);
  matmul_kernel<<<(n_nodes + 63) / 64, 256, 0, stream>>>(x, W, xw, n_nodes);

  long total = (long)n_nodes * OUT_SIZE;
  self_kernel<<<(int)((total + 255) / 256), 256, 0, stream>>>(dinv, xw, out,
                                                              total);

  long sthreads = (long)n_edges * 64;
  scatter_kernel<<<(int)((sthreads + 255) / 256), 256, 0, stream>>>(
      row, col, dinv, xw, out, n_edges);
}

// Round 2
// 759.347 us; speedup vs baseline: 1.1351x; 1.1351x over previous
//
#include <hip/hip_runtime.h>

#define IN_SIZE 256
#define OUT_SIZE 64
#define SCAN_CHUNK 1024  // 256 threads x 4 items per scan block

// ---------------------------------------------------------------------------
// Stage 1: integer degree histogram over non-self edges. count pre-zeroed.
__global__ __launch_bounds__(256) void deg_count_kernel(const int* __restrict__ row,
                                                        const int* __restrict__ col,
                                                        int* __restrict__ count,
                                                        int n_edges) {
  int e = blockIdx.x * 256 + threadIdx.x;
  if (e < n_edges) {
    int r = row[e], c = col[e];
    if (r != c) atomicAdd(&count[r], 1);
  }
}

// ---------------------------------------------------------------------------
// Stage 2a: per-block exclusive scan (256 thr x 4 items = 1024/block).
__global__ __launch_bounds__(256) void scan_block_kernel(const int* __restrict__ count,
                                                         int* __restrict__ row_start,
                                                         int* __restrict__ block_sums,
                                                         int n) {
  __shared__ int lds[256];
  int tid = threadIdx.x;
  int base = blockIdx.x * SCAN_CHUNK + tid * 4;
  int v[4];
  int s = 0;
#pragma unroll
  for (int i = 0; i < 4; i++) {
    int idx = base + i;
    v[i] = (idx < n) ? count[idx] : 0;
    s += v[i];
  }
  lds[tid] = s;
  __syncthreads();
  // Hillis-Steele inclusive scan over the 256 thread sums
  for (int off = 1; off < 256; off <<= 1) {
    int t = (tid >= off) ? lds[tid - off] : 0;
    __syncthreads();
    lds[tid] += t;
    __syncthreads();
  }
  int excl = (tid > 0) ? lds[tid - 1] : 0;
  if (tid == 255) block_sums[blockIdx.x] = lds[255];
  int run = excl;
#pragma unroll
  for (int i = 0; i < 4; i++) {
    int idx = base + i;
    if (idx < n) row_start[idx] = run;
    run += v[i];
  }
}

// Stage 2b: serial exclusive scan of the ~98 block sums (trivial work).
__global__ void scan_sums_kernel(int* __restrict__ block_sums, int nblocks) {
  if (threadIdx.x == 0 && blockIdx.x == 0) {
    int off = 0;
    for (int b = 0; b < nblocks; b++) {
      int t = block_sums[b];
      block_sums[b] = off;
      off += t;
    }
  }
}

// Stage 2c: add block offsets -> final row_start; init cursor; compute dinv.
__global__ __launch_bounds__(256) void finalize_kernel(const int* __restrict__ count,
                                                       int* __restrict__ row_start,
                                                       int* __restrict__ cursor,
                                                       float* __restrict__ dinv,
                                                       const int* __restrict__ block_sums,
                                                       int n) {
  int i = blockIdx.x * 256 + threadIdx.x;
  if (i < n) {
    int v = row_start[i] + block_sums[i / SCAN_CHUNK];
    row_start[i] = v;
    cursor[i] = v;
    dinv[i] = rsqrtf((float)count[i] + 1.0f);  // +1 = added self-loop
  }
}

// ---------------------------------------------------------------------------
// Stage 3: bucket edges by row (order within a row is irrelevant for the sum).
__global__ __launch_bounds__(256) void fill_kernel(const int* __restrict__ row,
                                                   const int* __restrict__ col,
                                                   int* __restrict__ cursor,
                                                   int* __restrict__ cols,
                                                   int n_edges) {
  int e = blockIdx.x * 256 + threadIdx.x;
  if (e < n_edges) {
    int r = row[e], c = col[e];
    if (r != c) {
      int slot = atomicAdd(&cursor[r], 1);
      cols[slot] = c;
    }
  }
}

// ---------------------------------------------------------------------------
// Stage 4: xw = x @ W.T   [N,256] x [64,256]^T -> [N,64], fp32.
__global__ __launch_bounds__(256) void matmul_kernel(const float* __restrict__ x,
                                                     const float* __restrict__ W,
                                                     float* __restrict__ xw,
                                                     int n_nodes) {
  int tid = threadIdx.x;
  int og = tid & 15;   // output group: cols og*4 .. og*4+3
  int ng = tid >> 4;   // node group 0..15
  long nbase = (long)blockIdx.x * 64 + (long)ng * 4;

  float acc[4][4];  // [out][node]
#pragma unroll
  for (int i = 0; i < 4; i++)
#pragma unroll
    for (int j = 0; j < 4; j++) acc[i][j] = 0.0f;

  for (int k = 0; k < IN_SIZE; k += 4) {
    float4 wv[4];
#pragma unroll
    for (int i = 0; i < 4; i++)
      wv[i] = *(const float4*)(W + (size_t)(og * 4 + i) * IN_SIZE + k);
#pragma unroll
    for (int j = 0; j < 4; j++) {
      long n = nbase + j;
      float4 xv = (n < n_nodes) ? *(const float4*)(x + n * IN_SIZE + k)
                                : make_float4(0.f, 0.f, 0.f, 0.f);
#pragma unroll
      for (int i = 0; i < 4; i++) {
        acc[i][j] += wv[i].x * xv.x + wv[i].y * xv.y + wv[i].z * xv.z +
                     wv[i].w * xv.w;
      }
    }
  }

#pragma unroll
  for (int j = 0; j < 4; j++) {
    long n = nbase + j;
    if (n < n_nodes) {
#pragma unroll
      for (int i = 0; i < 4; i++)
        xw[n * OUT_SIZE + og * 4 + i] = acc[i][j];
    }
  }
}

// ---------------------------------------------------------------------------
// Stage 5: CSR gather. One wave per row, one lane per output channel.
// out[r,:] = dinv[r] * ( dinv[r]*xw[r,:] + sum_c dinv[c]*xw[c,:] )
__global__ __launch_bounds__(256) void gather_kernel(const int* __restrict__ row_start,
                                                     const int* __restrict__ count,
                                                     const int* __restrict__ cols,
                                                     const float* __restrict__ dinv,
                                                     const float* __restrict__ xw,
                                                     float* __restrict__ out,
                                                     int n_nodes) {
  int lane = threadIdx.x & 63;
  int r = blockIdx.x * 4 + (threadIdx.x >> 6);
  if (r >= n_nodes) return;
  float dr = dinv[r];
  int start = row_start[r];
  int cnt = count[r];
  float acc = dr * xw[(long)r * OUT_SIZE + lane];  // self-loop term
  for (int j = 0; j < cnt; j++) {
    int c = cols[start + j];                       // wave-uniform broadcast
    acc += dinv[c] * xw[(long)c * OUT_SIZE + lane];  // coalesced 256B
  }
  out[(long)r * OUT_SIZE + lane] = dr * acc;
}

// ---------------------------------------------------------------------------
extern "C" void kernel_launch(void* const* d_in, const int* in_sizes, int n_in,
                              void* d_out, int out_size, void* d_ws,
                              size_t ws_size, hipStream_t stream) {
  const int* edge_index = (const int*)d_in[0];
  const float* x = (const float*)d_in[1];
  const float* W = (const float*)d_in[3];

  int n_edges = in_sizes[0] / 2;
  int n_nodes = in_sizes[1] / IN_SIZE;
  const int* row = edge_index;
  const int* col = edge_index + n_edges;
  float* out = (float*)d_out;

  // Workspace layout (16B-aligned chunks):
  // count[N] | row_start[N] | cursor[N] | dinv[N] | block_sums[1024] |
  // cols[E] | xw[N*64]
  char* ws = (char*)d_ws;
  size_t nb = ((size_t)n_nodes * 4 + 15) & ~(size_t)15;
  int* count = (int*)ws;
  int* row_start = (int*)(ws + nb);
  int* cursor = (int*)(ws + 2 * nb);
  float* dinv = (float*)(ws + 3 * nb);
  int* block_sums = (int*)(ws + 4 * nb);
  int* cols = (int*)(ws + 4 * nb + 4096);
  size_t eb = ((size_t)n_edges * 4 + 15) & ~(size_t)15;
  float* xw = (float*)(ws + 4 * nb + 4096 + eb);

  int nscan = (n_nodes + SCAN_CHUNK - 1) / SCAN_CHUNK;

  hipMemsetAsync(count, 0, (size_t)n_nodes * 4, stream);

  deg_count_kernel<<<(n_edges + 255) / 256, 256, 0, stream>>>(row, col, count,
                                                              n_edges);
  scan_block_kernel<<<nscan, 256, 0, stream>>>(count, row_start, block_sums,
                                               n_nodes);
  scan_sums_kernel<<<1, 64, 0, stream>>>(block_sums, nscan);
  finalize_kernel<<<(n_nodes + 255) / 256, 256, 0, stream>>>(
      count, row_start, cursor, dinv, block_sums, n_nodes);
  fill_kernel<<<(n_edges + 255) / 256, 256, 0, stream>>>(row, col, cursor,
                                                         cols, n_edges);
  matmul_kernel<<<(n_nodes + 63) / 64, 256, 0, stream>>>(x, W, xw, n_nodes);
  gather_kernel<<<(n_nodes + 3) / 4, 256, 0, stream>>>(
      row_start, count, cols, dinv, xw, out, n_nodes);
}

// Round 3
// 533.396 us; speedup vs baseline: 1.6159x; 1.4236x over previous
//
#include <hip/hip_runtime.h>

#define IN_SIZE 256
#define OUT_SIZE 64
#define SCAN_CHUNK 1024  // 256 threads x 4 items per scan block

typedef __attribute__((ext_vector_type(8))) short short8;   // 8 bf16, 4 VGPRs
typedef __attribute__((ext_vector_type(4))) float floatx4;  // MFMA acc

__device__ inline unsigned short f2bf(float f) {
  unsigned u = __builtin_bit_cast(unsigned, f);
  u += 0x7fff + ((u >> 16) & 1);  // round-to-nearest-even
  return (unsigned short)(u >> 16);
}

// ---------------------------------------------------------------------------
// Stage 0: W fp32 -> bf16 (one-time, 16384 elements).
__global__ __launch_bounds__(256) void wconv_kernel(const float* __restrict__ W,
                                                    unsigned short* __restrict__ Wb,
                                                    int total) {
  int i = blockIdx.x * 256 + threadIdx.x;
  if (i < total) Wb[i] = f2bf(W[i]);
}

// ---------------------------------------------------------------------------
// Stage 1: integer degree histogram over non-self edges. count pre-zeroed.
__global__ __launch_bounds__(256) void deg_count_kernel(const int* __restrict__ row,
                                                        const int* __restrict__ col,
                                                        int* __restrict__ count,
                                                        int n_edges) {
  int e = blockIdx.x * 256 + threadIdx.x;
  if (e < n_edges) {
    int r = row[e], c = col[e];
    if (r != c) atomicAdd(&count[r], 1);
  }
}

// ---------------------------------------------------------------------------
// Stage 2a: per-block exclusive scan (256 thr x 4 items = 1024/block).
__global__ __launch_bounds__(256) void scan_block_kernel(const int* __restrict__ count,
                                                         int* __restrict__ row_start,
                                                         int* __restrict__ block_sums,
                                                         int n) {
  __shared__ int lds[256];
  int tid = threadIdx.x;
  int base = blockIdx.x * SCAN_CHUNK + tid * 4;
  int v[4];
  int s = 0;
#pragma unroll
  for (int i = 0; i < 4; i++) {
    int idx = base + i;
    v[i] = (idx < n) ? count[idx] : 0;
    s += v[i];
  }
  lds[tid] = s;
  __syncthreads();
  for (int off = 1; off < 256; off <<= 1) {
    int t = (tid >= off) ? lds[tid - off] : 0;
    __syncthreads();
    lds[tid] += t;
    __syncthreads();
  }
  int excl = (tid > 0) ? lds[tid - 1] : 0;
  if (tid == 255) block_sums[blockIdx.x] = lds[255];
  int run = excl;
#pragma unroll
  for (int i = 0; i < 4; i++) {
    int idx = base + i;
    if (idx < n) row_start[idx] = run;
    run += v[i];
  }
}

// Stage 2b: serial exclusive scan of the ~98 block sums (trivial work).
__global__ void scan_sums_kernel(int* __restrict__ block_sums, int nblocks) {
  if (threadIdx.x == 0 && blockIdx.x == 0) {
    int off = 0;
    for (int b = 0; b < nblocks; b++) {
      int t = block_sums[b];
      block_sums[b] = off;
      off += t;
    }
  }
}

// Stage 2c: add block offsets -> final row_start; init cursor; compute dinv.
__global__ __launch_bounds__(256) void finalize_kernel(const int* __restrict__ count,
                                                       int* __restrict__ row_start,
                                                       int* __restrict__ cursor,
                                                       float* __restrict__ dinv,
                                                       const int* __restrict__ block_sums,
                                                       int n) {
  int i = blockIdx.x * 256 + threadIdx.x;
  if (i < n) {
    int v = row_start[i] + block_sums[i / SCAN_CHUNK];
    row_start[i] = v;
    cursor[i] = v;
    dinv[i] = rsqrtf((float)count[i] + 1.0f);  // +1 = added self-loop
  }
}

// ---------------------------------------------------------------------------
// Stage 3: bucket edges by row.
__global__ __launch_bounds__(256) void fill_kernel(const int* __restrict__ row,
                                                   const int* __restrict__ col,
                                                   int* __restrict__ cursor,
                                                   int* __restrict__ cols,
                                                   int n_edges) {
  int e = blockIdx.x * 256 + threadIdx.x;
  if (e < n_edges) {
    int r = row[e], c = col[e];
    if (r != c) {
      int slot = atomicAdd(&cursor[r], 1);
      cols[slot] = c;
    }
  }
}

// ---------------------------------------------------------------------------
// Stage 4: xw = x @ W.T via bf16 MFMA. Block = 256 thr = 4 waves = 64 nodes.
// LDS: full W (64x256 bf16) + x-tile in two K-halves (64x128 bf16).
// Row pads (+8 shorts) give stride 132/68 dwords -> <=2-way bank alias (free).
#define WPAD 264  // 256+8 shorts
#define XPAD 136  // 128+8 shorts
__global__ __launch_bounds__(256) void matmul_kernel(const float* __restrict__ x,
                                                     const unsigned short* __restrict__ Wb,
                                                     float* __restrict__ xw,
                                                     int n_nodes) {
  __shared__ unsigned short w_lds[64][WPAD];
  __shared__ unsigned short x_lds[64][XPAD];

  int tid = threadIdx.x;
  int wave = tid >> 6;
  int lane = tid & 63;
  int quad = lane >> 4;   // 0..3
  int lcol = lane & 15;   // 0..15
  long nbase = (long)blockIdx.x * 64;

  // --- stage W: 64x256 bf16 (32 KB). thread t: row t>>2, 64 shorts.
  {
    int r = tid >> 2;
    int q = tid & 3;
#pragma unroll
    for (int i = 0; i < 8; i++) {
      int c = q * 64 + i * 8;
      short8 v = *(const short8*)(Wb + (size_t)r * IN_SIZE + c);
      *(short8*)(&w_lds[r][c]) = v;
    }
  }

  floatx4 acc[4];
#pragma unroll
  for (int t = 0; t < 4; t++) acc[t] = (floatx4){0.f, 0.f, 0.f, 0.f};

  for (int h = 0; h < 2; h++) {
    // --- stage x half: 64 nodes x 128 k, fp32 -> bf16 in flight.
    {
      int r = tid >> 2;        // node within tile
      int q = tid & 3;         // 32-float chunk
      long node = nbase + r;
      const float* src = x + node * IN_SIZE + h * 128 + q * 32;
      bool ok = (node < (long)n_nodes);
#pragma unroll
      for (int i = 0; i < 4; i++) {  // 4 x (two float4 -> one short8)
        float4 a = ok ? *(const float4*)(src + i * 8)
                      : make_float4(0.f, 0.f, 0.f, 0.f);
        float4 b = ok ? *(const float4*)(src + i * 8 + 4)
                      : make_float4(0.f, 0.f, 0.f, 0.f);
        short8 v;
        v[0] = (short)f2bf(a.x); v[1] = (short)f2bf(a.y);
        v[2] = (short)f2bf(a.z); v[3] = (short)f2bf(a.w);
        v[4] = (short)f2bf(b.x); v[5] = (short)f2bf(b.y);
        v[6] = (short)f2bf(b.z); v[7] = (short)f2bf(b.w);
        *(short8*)(&x_lds[r][q * 32 + i * 8]) = v;
      }
    }
    __syncthreads();

    // --- MFMA: wave handles nodes wave*16..+15, 4 K-steps of 32 per half.
#pragma unroll
    for (int kk = 0; kk < 4; kk++) {
      short8 a = *(const short8*)(&x_lds[wave * 16 + lcol][kk * 32 + quad * 8]);
#pragma unroll
      for (int t = 0; t < 4; t++) {
        short8 b = *(const short8*)(
            &w_lds[t * 16 + lcol][h * 128 + kk * 32 + quad * 8]);
        acc[t] = __builtin_amdgcn_mfma_f32_16x16x32_bf16(a, b, acc[t], 0, 0, 0);
      }
    }
    __syncthreads();
  }

  // --- epilogue: C/D layout col=lane&15, row=quad*4+reg.
#pragma unroll
  for (int t = 0; t < 4; t++) {
#pragma unroll
    for (int reg = 0; reg < 4; reg++) {
      long node = nbase + wave * 16 + quad * 4 + reg;
      if (node < (long)n_nodes)
        xw[node * OUT_SIZE + t * 16 + lcol] = acc[t][reg];
    }
  }
}

// ---------------------------------------------------------------------------
// Stage 5: CSR gather. One wave per row, one lane per output channel.
__global__ __launch_bounds__(256) void gather_kernel(const int* __restrict__ row_start,
                                                     const int* __restrict__ count,
                                                     const int* __restrict__ cols,
                                                     const float* __restrict__ dinv,
                                                     const float* __restrict__ xw,
                                                     float* __restrict__ out,
                                                     int n_nodes) {
  int lane = threadIdx.x & 63;
  int r = blockIdx.x * 4 + (threadIdx.x >> 6);
  if (r >= n_nodes) return;
  float dr = dinv[r];
  int start = row_start[r];
  int cnt = count[r];
  float acc = dr * xw[(long)r * OUT_SIZE + lane];  // self-loop term
  for (int j = 0; j < cnt; j++) {
    int c = cols[start + j];
    acc += dinv[c] * xw[(long)c * OUT_SIZE + lane];
  }
  out[(long)r * OUT_SIZE + lane] = dr * acc;
}

// ---------------------------------------------------------------------------
extern "C" void kernel_launch(void* const* d_in, const int* in_sizes, int n_in,
                              void* d_out, int out_size, void* d_ws,
                              size_t ws_size, hipStream_t stream) {
  const int* edge_index = (const int*)d_in[0];
  const float* x = (const float*)d_in[1];
  const float* W = (const float*)d_in[3];

  int n_edges = in_sizes[0] / 2;
  int n_nodes = in_sizes[1] / IN_SIZE;
  const int* row = edge_index;
  const int* col = edge_index + n_edges;
  float* out = (float*)d_out;

  // Workspace: count[N] | row_start[N] | cursor[N] | dinv[N] | block_sums |
  //            cols[E] | xw[N*64 f32] | Wb[64*256 bf16]
  char* ws = (char*)d_ws;
  size_t nb = ((size_t)n_nodes * 4 + 15) & ~(size_t)15;
  int* count = (int*)ws;
  int* row_start = (int*)(ws + nb);
  int* cursor = (int*)(ws + 2 * nb);
  float* dinv = (float*)(ws + 3 * nb);
  int* block_sums = (int*)(ws + 4 * nb);
  int* cols = (int*)(ws + 4 * nb + 4096);
  size_t eb = ((size_t)n_edges * 4 + 15) & ~(size_t)15;
  float* xw = (float*)(ws + 4 * nb + 4096 + eb);
  unsigned short* Wb =
      (unsigned short*)(ws + 4 * nb + 4096 + eb + (size_t)n_nodes * OUT_SIZE * 4);

  int nscan = (n_nodes + SCAN_CHUNK - 1) / SCAN_CHUNK;

  hipMemsetAsync(count, 0, (size_t)n_nodes * 4, stream);

  wconv_kernel<<<(OUT_SIZE * IN_SIZE + 255) / 256, 256, 0, stream>>>(
      W, Wb, OUT_SIZE * IN_SIZE);
  deg_count_kernel<<<(n_edges + 255) / 256, 256, 0, stream>>>(row, col, count,
                                                              n_edges);
  scan_block_kernel<<<nscan, 256, 0, stream>>>(count, row_start, block_sums,
                                               n_nodes);
  scan_sums_kernel<<<1, 64, 0, stream>>>(block_sums, nscan);
  finalize_kernel<<<(n_nodes + 255) / 256, 256, 0, stream>>>(
      count, row_start, cursor, dinv, block_sums, n_nodes);
  fill_kernel<<<(n_edges + 255) / 256, 256, 0, stream>>>(row, col, cursor,
                                                         cols, n_edges);
  matmul_kernel<<<(n_nodes + 63) / 64, 256, 0, stream>>>(x, Wb, xw, n_nodes);
  gather_kernel<<<(n_nodes + 3) / 4, 256, 0, stream>>>(
      row_start, count, cols, dinv, xw, out, n_nodes);
}

// Round 4
// 428.606 us; speedup vs baseline: 2.0110x; 1.2445x over previous
//
#include <hip/hip_runtime.h>

#define IN_SIZE 256
#define OUT_SIZE 64
#define SCAN_CHUNK 1024  // 256 threads x 4 items per scan block

typedef __attribute__((ext_vector_type(8))) short short8;   // 8 bf16, 4 VGPRs
typedef __attribute__((ext_vector_type(4))) float floatx4;  // MFMA acc

__device__ inline unsigned short f2bf(float f) {
  unsigned u = __builtin_bit_cast(unsigned, f);
  u += 0x7fff + ((u >> 16) & 1);  // round-to-nearest-even
  return (unsigned short)(u >> 16);
}
__device__ inline float bf2f(unsigned short u) {
  unsigned v = (unsigned)u << 16;
  return __builtin_bit_cast(float, v);
}

// ---------------------------------------------------------------------------
// Stage 1: integer degree histogram over non-self edges. count pre-zeroed.
__global__ __launch_bounds__(256) void deg_count_kernel(const int* __restrict__ row,
                                                        const int* __restrict__ col,
                                                        int* __restrict__ count,
                                                        int n_edges) {
  int e = blockIdx.x * 256 + threadIdx.x;
  if (e < n_edges) {
    int r = row[e], c = col[e];
    if (r != c) atomicAdd(&count[r], 1);
  }
}

// ---------------------------------------------------------------------------
// Stage 2a: per-block exclusive scan (256 thr x 4 items = 1024/block).
__global__ __launch_bounds__(256) void scan_block_kernel(const int* __restrict__ count,
                                                         int* __restrict__ row_start,
                                                         int* __restrict__ block_sums,
                                                         int n) {
  __shared__ int lds[256];
  int tid = threadIdx.x;
  int base = blockIdx.x * SCAN_CHUNK + tid * 4;
  int v[4];
  int s = 0;
#pragma unroll
  for (int i = 0; i < 4; i++) {
    int idx = base + i;
    v[i] = (idx < n) ? count[idx] : 0;
    s += v[i];
  }
  lds[tid] = s;
  __syncthreads();
  for (int off = 1; off < 256; off <<= 1) {
    int t = (tid >= off) ? lds[tid - off] : 0;
    __syncthreads();
    lds[tid] += t;
    __syncthreads();
  }
  int excl = (tid > 0) ? lds[tid - 1] : 0;
  if (tid == 255) block_sums[blockIdx.x] = lds[255];
  int run = excl;
#pragma unroll
  for (int i = 0; i < 4; i++) {
    int idx = base + i;
    if (idx < n) row_start[idx] = run;
    run += v[i];
  }
}

// Stage 2b: one-block parallel exclusive scan of the <=128 block sums.
// (Was a serial 98-iteration dependent-load loop: ~25us of pure latency.)
__global__ __launch_bounds__(128) void scan_sums_kernel(int* __restrict__ block_sums,
                                                        int nblocks) {
  __shared__ int lds[128];
  int tid = threadIdx.x;
  int v = (tid < nblocks) ? block_sums[tid] : 0;
  lds[tid] = v;
  __syncthreads();
  for (int off = 1; off < 128; off <<= 1) {
    int t = (tid >= off) ? lds[tid - off] : 0;
    __syncthreads();
    lds[tid] += t;
    __syncthreads();
  }
  int excl = (tid > 0) ? lds[tid - 1] : 0;
  if (tid < nblocks) block_sums[tid] = excl;
}

// Stage 2c: add block offsets -> final row_start; init cursor; compute dinv.
__global__ __launch_bounds__(256) void finalize_kernel(const int* __restrict__ count,
                                                       int* __restrict__ row_start,
                                                       int* __restrict__ cursor,
                                                       float* __restrict__ dinv,
                                                       const int* __restrict__ block_sums,
                                                       int n) {
  int i = blockIdx.x * 256 + threadIdx.x;
  if (i < n) {
    int v = row_start[i] + block_sums[i / SCAN_CHUNK];
    row_start[i] = v;
    cursor[i] = v;
    dinv[i] = rsqrtf((float)count[i] + 1.0f);  // +1 = added self-loop
  }
}

// ---------------------------------------------------------------------------
// Stage 3: bucket edges by row.
__global__ __launch_bounds__(256) void fill_kernel(const int* __restrict__ row,
                                                   const int* __restrict__ col,
                                                   int* __restrict__ cursor,
                                                   int* __restrict__ cols,
                                                   int n_edges) {
  int e = blockIdx.x * 256 + threadIdx.x;
  if (e < n_edges) {
    int r = row[e], c = col[e];
    if (r != c) {
      int slot = atomicAdd(&cursor[r], 1);
      cols[slot] = c;
    }
  }
}

// ---------------------------------------------------------------------------
// Stage 4: xwd = dinv * (x @ W.T), output bf16 [N][64].
// Block = 256 thr = 4 waves = 64 nodes. W staged fp32->bf16 in-flight (no
// separate conversion kernel; W is L2-resident across all blocks).
// MFMA with A=W (m=channel), B=x (n=node): D[m=ch][n=node] -> lane holds
// node=lane&15 fixed, channels quad*4+reg -> ushort4 contiguous stores.
#define WPAD 264  // 256+8 shorts
#define XPAD 136  // 128+8 shorts
__global__ __launch_bounds__(256) void matmul_kernel(const float* __restrict__ x,
                                                     const float* __restrict__ W,
                                                     const float* __restrict__ dinv,
                                                     unsigned short* __restrict__ xwd,
                                                     int n_nodes) {
  __shared__ unsigned short w_lds[64][WPAD];
  __shared__ unsigned short x_lds[64][XPAD];

  int tid = threadIdx.x;
  int wave = tid >> 6;
  int lane = tid & 63;
  int quad = lane >> 4;   // 0..3
  int lcol = lane & 15;   // 0..15
  long nbase = (long)blockIdx.x * 64;

  // --- stage W: 64x256 fp32 -> bf16. thread t: row t>>2, 64 floats.
  {
    int r = tid >> 2;
    int q = tid & 3;
    const float* src = W + (size_t)r * IN_SIZE;
#pragma unroll
    for (int i = 0; i < 8; i++) {
      int c = q * 64 + i * 8;
      float4 a = *(const float4*)(src + c);
      float4 b = *(const float4*)(src + c + 4);
      short8 v;
      v[0] = (short)f2bf(a.x); v[1] = (short)f2bf(a.y);
      v[2] = (short)f2bf(a.z); v[3] = (short)f2bf(a.w);
      v[4] = (short)f2bf(b.x); v[5] = (short)f2bf(b.y);
      v[6] = (short)f2bf(b.z); v[7] = (short)f2bf(b.w);
      *(short8*)(&w_lds[r][c]) = v;
    }
  }

  floatx4 acc[4];
#pragma unroll
  for (int t = 0; t < 4; t++) acc[t] = (floatx4){0.f, 0.f, 0.f, 0.f};

  for (int h = 0; h < 2; h++) {
    // --- stage x half: 64 nodes x 128 k, fp32 -> bf16 in flight.
    {
      int r = tid >> 2;        // node within tile
      int q = tid & 3;         // 32-float chunk
      long node = nbase + r;
      const float* src = x + node * IN_SIZE + h * 128 + q * 32;
      bool ok = (node < (long)n_nodes);
#pragma unroll
      for (int i = 0; i < 4; i++) {
        float4 a = ok ? *(const float4*)(src + i * 8)
                      : make_float4(0.f, 0.f, 0.f, 0.f);
        float4 b = ok ? *(const float4*)(src + i * 8 + 4)
                      : make_float4(0.f, 0.f, 0.f, 0.f);
        short8 v;
        v[0] = (short)f2bf(a.x); v[1] = (short)f2bf(a.y);
        v[2] = (short)f2bf(a.z); v[3] = (short)f2bf(a.w);
        v[4] = (short)f2bf(b.x); v[5] = (short)f2bf(b.y);
        v[6] = (short)f2bf(b.z); v[7] = (short)f2bf(b.w);
        *(short8*)(&x_lds[r][q * 32 + i * 8]) = v;
      }
    }
    __syncthreads();

    // --- MFMA: A = W rows (ch), B = x rows (node). Wave -> nodes wave*16..+15.
#pragma unroll
    for (int kk = 0; kk < 4; kk++) {
      short8 b = *(const short8*)(&x_lds[wave * 16 + lcol][kk * 32 + quad * 8]);
#pragma unroll
      for (int t = 0; t < 4; t++) {
        short8 a = *(const short8*)(
            &w_lds[t * 16 + lcol][h * 128 + kk * 32 + quad * 8]);
        acc[t] = __builtin_amdgcn_mfma_f32_16x16x32_bf16(a, b, acc[t], 0, 0, 0);
      }
    }
    __syncthreads();
  }

  // --- epilogue: D[m=ch][n=node]; lane: node = lcol, ch = quad*4+reg.
  long node = nbase + wave * 16 + lcol;
  if (node < (long)n_nodes) {
    float dv = dinv[node];
#pragma unroll
    for (int t = 0; t < 4; t++) {
      ushort4 sv;
      sv.x = f2bf(dv * acc[t][0]);
      sv.y = f2bf(dv * acc[t][1]);
      sv.z = f2bf(dv * acc[t][2]);
      sv.w = f2bf(dv * acc[t][3]);
      *(ushort4*)(xwd + node * OUT_SIZE + t * 16 + quad * 4) = sv;
    }
  }
}

// ---------------------------------------------------------------------------
// Stage 5: CSR gather. One wave per row; 4 edges per iteration.
// lane = sub(0..3: edge slot) x cg(0..15: channel group of 4).
// out[r,:] = dinv[r] * ( xwd[r,:] + sum_c xwd[c,:] ),  xwd = dinv*xw (bf16).
__global__ __launch_bounds__(256) void gather_kernel(const int* __restrict__ row_start,
                                                     const int* __restrict__ count,
                                                     const int* __restrict__ cols,
                                                     const float* __restrict__ dinv,
                                                     const unsigned short* __restrict__ xwd,
                                                     float* __restrict__ out,
                                                     int n_nodes) {
  int lane = threadIdx.x & 63;
  int r = blockIdx.x * 4 + (threadIdx.x >> 6);
  if (r >= n_nodes) return;
  int sub = lane >> 4;   // edge slot 0..3
  int cg = lane & 15;    // channels cg*4 .. cg*4+3
  int start = row_start[r];
  int cnt = count[r];

  float a0 = 0.f, a1 = 0.f, a2 = 0.f, a3 = 0.f;
  if (sub == 0) {  // self-loop term, once
    ushort4 v = *(const ushort4*)(xwd + (size_t)r * OUT_SIZE + cg * 4);
    a0 = bf2f(v.x); a1 = bf2f(v.y); a2 = bf2f(v.z); a3 = bf2f(v.w);
  }
  for (int j = 0; j < cnt; j += 4) {
    int idx = j + sub;
    bool act = idx < cnt;
    int c = act ? cols[start + idx] : r;  // dummy -> hot line, masked out
    ushort4 v = *(const ushort4*)(xwd + (size_t)c * OUT_SIZE + cg * 4);
    float m = act ? 1.0f : 0.0f;
    a0 += m * bf2f(v.x);
    a1 += m * bf2f(v.y);
    a2 += m * bf2f(v.z);
    a3 += m * bf2f(v.w);
  }
  // butterfly-combine the 4 edge slots (lanes differing in bits 4,5)
  a0 += __shfl_xor(a0, 16); a0 += __shfl_xor(a0, 32);
  a1 += __shfl_xor(a1, 16); a1 += __shfl_xor(a1, 32);
  a2 += __shfl_xor(a2, 16); a2 += __shfl_xor(a2, 32);
  a3 += __shfl_xor(a3, 16); a3 += __shfl_xor(a3, 32);

  if (sub == 0) {
    float dr = dinv[r];
    float4 o = make_float4(dr * a0, dr * a1, dr * a2, dr * a3);
    *(float4*)(out + (size_t)r * OUT_SIZE + cg * 4) = o;
  }
}

// ---------------------------------------------------------------------------
extern "C" void kernel_launch(void* const* d_in, const int* in_sizes, int n_in,
                              void* d_out, int out_size, void* d_ws,
                              size_t ws_size, hipStream_t stream) {
  const int* edge_index = (const int*)d_in[0];
  const float* x = (const float*)d_in[1];
  const float* W = (const float*)d_in[3];

  int n_edges = in_sizes[0] / 2;
  int n_nodes = in_sizes[1] / IN_SIZE;
  const int* row = edge_index;
  const int* col = edge_index + n_edges;
  float* out = (float*)d_out;

  // Workspace: count[N] | row_start[N] | cursor[N] | dinv[N] | block_sums |
  //            cols[E] | xwd[N*64 bf16]
  char* ws = (char*)d_ws;
  size_t nb = ((size_t)n_nodes * 4 + 15) & ~(size_t)15;
  int* count = (int*)ws;
  int* row_start = (int*)(ws + nb);
  int* cursor = (int*)(ws + 2 * nb);
  float* dinv = (float*)(ws + 3 * nb);
  int* block_sums = (int*)(ws + 4 * nb);
  int* cols = (int*)(ws + 4 * nb + 4096);
  size_t eb = ((size_t)n_edges * 4 + 15) & ~(size_t)15;
  unsigned short* xwd = (unsigned short*)(ws + 4 * nb + 4096 + eb);

  int nscan = (n_nodes + SCAN_CHUNK - 1) / SCAN_CHUNK;  // 98 <= 128

  hipMemsetAsync(count, 0, (size_t)n_nodes * 4, stream);

  deg_count_kernel<<<(n_edges + 255) / 256, 256, 0, stream>>>(row, col, count,
                                                              n_edges);
  scan_block_kernel<<<nscan, 256, 0, stream>>>(count, row_start, block_sums,
                                               n_nodes);
  scan_sums_kernel<<<1, 128, 0, stream>>>(block_sums, nscan);
  finalize_kernel<<<(n_nodes + 255) / 256, 256, 0, stream>>>(
      count, row_start, cursor, dinv, block_sums, n_nodes);
  fill_kernel<<<(n_edges + 255) / 256, 256, 0, stream>>>(row, col, cursor,
                                                         cols, n_edges);
  matmul_kernel<<<(n_nodes + 63) / 64, 256, 0, stream>>>(x, W, dinv, xwd,
                                                         n_nodes);
  gather_kernel<<<(n_nodes + 3) / 4, 256, 0, stream>>>(
      row_start, count, cols, dinv, xwd, out, n_nodes);
}

// Round 5
// 288.139 us; speedup vs baseline: 2.9913x; 1.4875x over previous
//
#include <hip/hip_runtime.h>

#define IN_SIZE 256
#define OUT_SIZE 64
#define CAP 10240        // coarse-bucket capacity: mean 8192, sigma 90 -> +22 sigma
#define K1_TILE 4096     // edges per K1 block (16 per thread)

typedef __attribute__((ext_vector_type(8))) short short8;   // 8 bf16, 4 VGPRs
typedef __attribute__((ext_vector_type(4))) float floatx4;  // MFMA acc

__device__ inline unsigned short f2bf(float f) {
  unsigned u = __builtin_bit_cast(unsigned, f);
  u += 0x7fff + ((u >> 16) & 1);  // round-to-nearest-even
  return (unsigned short)(u >> 16);
}
__device__ inline float bf2f(unsigned short u) {
  unsigned v = (unsigned)u << 16;
  return __builtin_bit_cast(float, v);
}

// ---------------------------------------------------------------------------
// K1: coarse bucketing by row>>9 into 196 padded regions.
// Per block: LDS hist over its 4096-edge tile -> ONE global atomicAdd per
// (block,bucket) to reserve a range (77K global atomics total vs 1.6M before)
// -> scatter packed ((row&511)<<17 | col) via LDS-cursor ranks.
__global__ __launch_bounds__(256) void bucket_coarse_kernel(
    const int* __restrict__ row, const int* __restrict__ col,
    int* __restrict__ coarse_cursor, unsigned* __restrict__ pairs,
    int n_edges, int nbuck) {
  __shared__ int hist[256];   // >= nbuck (196)
  int tid = threadIdx.x;
  hist[tid] = 0;
  __syncthreads();

  int r[16], c[16];
  int ebase = blockIdx.x * K1_TILE + tid;
#pragma unroll
  for (int i = 0; i < 16; i++) {
    int e = ebase + i * 256;
    bool ok = e < n_edges;
    r[i] = ok ? row[e] : -1;
    c[i] = ok ? col[e] : -1;
    if (ok && r[i] != c[i]) atomicAdd(&hist[r[i] >> 9], 1);
  }
  __syncthreads();

  // reserve: LDS cursor <- global base for this block's run in each bucket
  if (tid < nbuck) {
    int cnt = hist[tid];
    hist[tid] = atomicAdd(&coarse_cursor[tid], cnt);
  }
  __syncthreads();

#pragma unroll
  for (int i = 0; i < 16; i++) {
    if (r[i] >= 0 && r[i] != c[i]) {
      int bin = r[i] >> 9;
      int slot = atomicAdd(&hist[bin], 1);  // LDS atomic -> in-bucket slot
      if (slot < CAP)
        pairs[(size_t)bin * CAP + slot] =
            ((unsigned)(r[i] & 511) << 17) | (unsigned)c[i];
    }
  }
}

// ---------------------------------------------------------------------------
// K2: fine grouping within each coarse bucket (one block per bucket).
// LDS 512-bin hist == per-row degree (block owns rows [b*512,b*512+512):
// plain stores for count/row_start/dinv, NO atomics) -> LDS scan -> scatter
// cols to final positions in colsp.
__global__ __launch_bounds__(256) void bucket_fine_kernel(
    const int* __restrict__ coarse_cursor, const unsigned* __restrict__ pairs,
    unsigned* __restrict__ colsp, int* __restrict__ count,
    int* __restrict__ row_start, float* __restrict__ dinv, int n_nodes) {
  __shared__ int hist[512];
  __shared__ int ssum[256];
  int tid = threadIdx.x;
  int b = blockIdx.x;
  size_t base = (size_t)b * CAP;
  int n_b = coarse_cursor[b];
  if (n_b > CAP) n_b = CAP;

  hist[tid] = 0;
  hist[tid + 256] = 0;
  __syncthreads();

  for (int i = tid; i < n_b; i += 256)
    atomicAdd(&hist[pairs[base + i] >> 17], 1);
  __syncthreads();

  // exclusive scan of hist[512]: each thread owns f=2*tid, 2*tid+1
  int v0 = hist[2 * tid], v1 = hist[2 * tid + 1];
  ssum[tid] = v0 + v1;
  __syncthreads();
  for (int off = 1; off < 256; off <<= 1) {
    int t = (tid >= off) ? ssum[tid - off] : 0;
    __syncthreads();
    ssum[tid] += t;
    __syncthreads();
  }
  int e0 = (tid > 0) ? ssum[tid - 1] : 0;
  int e1 = e0 + v0;

  // per-row outputs (rows b*512+f, disjoint across blocks -> plain stores)
  {
    int r0 = b * 512 + 2 * tid;
    if (r0 < n_nodes) {
      count[r0] = v0;
      row_start[r0] = (int)base + e0;
      dinv[r0] = rsqrtf((float)v0 + 1.0f);
    }
    int r1 = r0 + 1;
    if (r1 < n_nodes) {
      count[r1] = v1;
      row_start[r1] = (int)base + e1;
      dinv[r1] = rsqrtf((float)v1 + 1.0f);
    }
  }
  // reuse hist as scatter cursors
  hist[2 * tid] = e0;
  hist[2 * tid + 1] = e1;
  __syncthreads();

  for (int i = tid; i < n_b; i += 256) {
    unsigned p = pairs[base + i];
    int slot = atomicAdd(&hist[p >> 17], 1);  // LDS atomic
    colsp[base + slot] = p & 0x1FFFFu;
  }
}

// ---------------------------------------------------------------------------
// Stage 4: xwd = dinv * (x @ W.T), output bf16 [N][64].
#define WPAD 264  // 256+8 shorts
#define XPAD 136  // 128+8 shorts
__global__ __launch_bounds__(256) void matmul_kernel(const float* __restrict__ x,
                                                     const float* __restrict__ W,
                                                     const float* __restrict__ dinv,
                                                     unsigned short* __restrict__ xwd,
                                                     int n_nodes) {
  __shared__ unsigned short w_lds[64][WPAD];
  __shared__ unsigned short x_lds[64][XPAD];

  int tid = threadIdx.x;
  int wave = tid >> 6;
  int lane = tid & 63;
  int quad = lane >> 4;   // 0..3
  int lcol = lane & 15;   // 0..15
  long nbase = (long)blockIdx.x * 64;

  // --- stage W: 64x256 fp32 -> bf16 in flight.
  {
    int r = tid >> 2;
    int q = tid & 3;
    const float* src = W + (size_t)r * IN_SIZE;
#pragma unroll
    for (int i = 0; i < 8; i++) {
      int c = q * 64 + i * 8;
      float4 a = *(const float4*)(src + c);
      float4 bb = *(const float4*)(src + c + 4);
      short8 v;
      v[0] = (short)f2bf(a.x); v[1] = (short)f2bf(a.y);
      v[2] = (short)f2bf(a.z); v[3] = (short)f2bf(a.w);
      v[4] = (short)f2bf(bb.x); v[5] = (short)f2bf(bb.y);
      v[6] = (short)f2bf(bb.z); v[7] = (short)f2bf(bb.w);
      *(short8*)(&w_lds[r][c]) = v;
    }
  }

  floatx4 acc[4];
#pragma unroll
  for (int t = 0; t < 4; t++) acc[t] = (floatx4){0.f, 0.f, 0.f, 0.f};

  for (int h = 0; h < 2; h++) {
    {
      int r = tid >> 2;
      int q = tid & 3;
      long node = nbase + r;
      const float* src = x + node * IN_SIZE + h * 128 + q * 32;
      bool ok = (node < (long)n_nodes);
#pragma unroll
      for (int i = 0; i < 4; i++) {
        float4 a = ok ? *(const float4*)(src + i * 8)
                      : make_float4(0.f, 0.f, 0.f, 0.f);
        float4 bb = ok ? *(const float4*)(src + i * 8 + 4)
                       : make_float4(0.f, 0.f, 0.f, 0.f);
        short8 v;
        v[0] = (short)f2bf(a.x); v[1] = (short)f2bf(a.y);
        v[2] = (short)f2bf(a.z); v[3] = (short)f2bf(a.w);
        v[4] = (short)f2bf(bb.x); v[5] = (short)f2bf(bb.y);
        v[6] = (short)f2bf(bb.z); v[7] = (short)f2bf(bb.w);
        *(short8*)(&x_lds[r][q * 32 + i * 8]) = v;
      }
    }
    __syncthreads();

#pragma unroll
    for (int kk = 0; kk < 4; kk++) {
      short8 bfrag = *(const short8*)(&x_lds[wave * 16 + lcol][kk * 32 + quad * 8]);
#pragma unroll
      for (int t = 0; t < 4; t++) {
        short8 afrag = *(const short8*)(
            &w_lds[t * 16 + lcol][h * 128 + kk * 32 + quad * 8]);
        acc[t] =
            __builtin_amdgcn_mfma_f32_16x16x32_bf16(afrag, bfrag, acc[t], 0, 0, 0);
      }
    }
    __syncthreads();
  }

  // --- epilogue: D[m=ch][n=node]; lane: node = lcol, ch = quad*4+reg.
  long node = nbase + wave * 16 + lcol;
  if (node < (long)n_nodes) {
    float dv = dinv[node];
#pragma unroll
    for (int t = 0; t < 4; t++) {
      ushort4 sv;
      sv.x = f2bf(dv * acc[t][0]);
      sv.y = f2bf(dv * acc[t][1]);
      sv.z = f2bf(dv * acc[t][2]);
      sv.w = f2bf(dv * acc[t][3]);
      *(ushort4*)(xwd + node * OUT_SIZE + t * 16 + quad * 4) = sv;
    }
  }
}

// ---------------------------------------------------------------------------
// Stage 5: CSR gather. One wave per row; 4 edges per iteration.
__global__ __launch_bounds__(256) void gather_kernel(const int* __restrict__ row_start,
                                                     const int* __restrict__ count,
                                                     const unsigned* __restrict__ colsp,
                                                     const float* __restrict__ dinv,
                                                     const unsigned short* __restrict__ xwd,
                                                     float* __restrict__ out,
                                                     int n_nodes) {
  int lane = threadIdx.x & 63;
  int r = blockIdx.x * 4 + (threadIdx.x >> 6);
  if (r >= n_nodes) return;
  int sub = lane >> 4;   // edge slot 0..3
  int cg = lane & 15;    // channels cg*4 .. cg*4+3
  int start = row_start[r];
  int cnt = count[r];

  float a0 = 0.f, a1 = 0.f, a2 = 0.f, a3 = 0.f;
  if (sub == 0) {  // self-loop term, once
    ushort4 v = *(const ushort4*)(xwd + (size_t)r * OUT_SIZE + cg * 4);
    a0 = bf2f(v.x); a1 = bf2f(v.y); a2 = bf2f(v.z); a3 = bf2f(v.w);
  }
  for (int j = 0; j < cnt; j += 4) {
    int idx = j + sub;
    bool act = idx < cnt;
    int c = act ? (int)colsp[start + idx] : r;
    ushort4 v = *(const ushort4*)(xwd + (size_t)c * OUT_SIZE + cg * 4);
    float m = act ? 1.0f : 0.0f;
    a0 += m * bf2f(v.x);
    a1 += m * bf2f(v.y);
    a2 += m * bf2f(v.z);
    a3 += m * bf2f(v.w);
  }
  a0 += __shfl_xor(a0, 16); a0 += __shfl_xor(a0, 32);
  a1 += __shfl_xor(a1, 16); a1 += __shfl_xor(a1, 32);
  a2 += __shfl_xor(a2, 16); a2 += __shfl_xor(a2, 32);
  a3 += __shfl_xor(a3, 16); a3 += __shfl_xor(a3, 32);

  if (sub == 0) {
    float dr = dinv[r];
    float4 o = make_float4(dr * a0, dr * a1, dr * a2, dr * a3);
    *(float4*)(out + (size_t)r * OUT_SIZE + cg * 4) = o;
  }
}

// ---------------------------------------------------------------------------
extern "C" void kernel_launch(void* const* d_in, const int* in_sizes, int n_in,
                              void* d_out, int out_size, void* d_ws,
                              size_t ws_size, hipStream_t stream) {
  const int* edge_index = (const int*)d_in[0];
  const float* x = (const float*)d_in[1];
  const float* W = (const float*)d_in[3];

  int n_edges = in_sizes[0] / 2;
  int n_nodes = in_sizes[1] / IN_SIZE;
  const int* row = edge_index;
  const int* col = edge_index + n_edges;
  float* out = (float*)d_out;

  int nbuck = (n_nodes + 511) >> 9;  // 196

  // Workspace: count[N] | row_start[N] | dinv[N] | coarse_cursor(4KB) |
  //            pairs[nbuck*CAP u32] | colsp[nbuck*CAP u32] | xwd[N*64 bf16]
  char* ws = (char*)d_ws;
  size_t nb = ((size_t)n_nodes * 4 + 15) & ~(size_t)15;
  int* count = (int*)ws;
  int* row_start = (int*)(ws + nb);
  float* dinv = (float*)(ws + 2 * nb);
  int* coarse_cursor = (int*)(ws + 3 * nb);
  size_t bucketsB = (size_t)nbuck * CAP * 4;
  unsigned* pairs = (unsigned*)(ws + 3 * nb + 4096);
  unsigned* colsp = (unsigned*)(ws + 3 * nb + 4096 + bucketsB);
  unsigned short* xwd =
      (unsigned short*)(ws + 3 * nb + 4096 + 2 * bucketsB);

  hipMemsetAsync(coarse_cursor, 0, (size_t)nbuck * 4, stream);

  int nb1 = (n_edges + K1_TILE - 1) / K1_TILE;
  bucket_coarse_kernel<<<nb1, 256, 0, stream>>>(row, col, coarse_cursor,
                                                pairs, n_edges, nbuck);
  bucket_fine_kernel<<<nbuck, 256, 0, stream>>>(coarse_cursor, pairs, colsp,
                                                count, row_start, dinv,
                                                n_nodes);
  matmul_kernel<<<(n_nodes + 63) / 64, 256, 0, stream>>>(x, W, dinv, xwd,
                                                         n_nodes);
  gather_kernel<<<(n_nodes + 3) / 4, 256, 0, stream>>>(
      row_start, count, colsp, dinv, xwd, out, n_nodes);
}

// Round 6
// 278.285 us; speedup vs baseline: 3.0973x; 1.0354x over previous
//
#include <hip/hip_runtime.h>

#define IN_SIZE 256
#define OUT_SIZE 64
#define CAP 10240        // coarse-bucket capacity: mean 8192, sigma 90 -> +22 sigma
#define K1_TILE 4096     // edges per K1 block (16 per thread)

typedef __attribute__((ext_vector_type(8))) short short8;   // 8 bf16, 4 VGPRs
typedef __attribute__((ext_vector_type(4))) float floatx4;  // MFMA acc

__device__ inline unsigned short f2bf(float f) {
  unsigned u = __builtin_bit_cast(unsigned, f);
  u += 0x7fff + ((u >> 16) & 1);  // round-to-nearest-even
  return (unsigned short)(u >> 16);
}
__device__ inline float bf2f(unsigned short u) {
  unsigned v = (unsigned)u << 16;
  return __builtin_bit_cast(float, v);
}

// ---------------------------------------------------------------------------
// Stage 0: W fp32 -> bf16 once (16384 elems, ~2us). Removes per-block f2bf
// of W from the matmul (1563 blocks x 16K conversions).
__global__ __launch_bounds__(256) void wconv_kernel(const float* __restrict__ W,
                                                    unsigned short* __restrict__ Wb,
                                                    int total) {
  int i = blockIdx.x * 256 + threadIdx.x;
  if (i < total) Wb[i] = f2bf(W[i]);
}

// ---------------------------------------------------------------------------
// K1: coarse bucketing by row>>9 into 196 padded regions.
__global__ __launch_bounds__(256) void bucket_coarse_kernel(
    const int* __restrict__ row, const int* __restrict__ col,
    int* __restrict__ coarse_cursor, unsigned* __restrict__ pairs,
    int n_edges, int nbuck) {
  __shared__ int hist[256];   // >= nbuck (196)
  int tid = threadIdx.x;
  hist[tid] = 0;
  __syncthreads();

  int r[16], c[16];
  int ebase = blockIdx.x * K1_TILE + tid;
#pragma unroll
  for (int i = 0; i < 16; i++) {
    int e = ebase + i * 256;
    bool ok = e < n_edges;
    r[i] = ok ? row[e] : -1;
    c[i] = ok ? col[e] : -1;
    if (ok && r[i] != c[i]) atomicAdd(&hist[r[i] >> 9], 1);
  }
  __syncthreads();

  if (tid < nbuck) {
    int cnt = hist[tid];
    hist[tid] = atomicAdd(&coarse_cursor[tid], cnt);
  }
  __syncthreads();

#pragma unroll
  for (int i = 0; i < 16; i++) {
    if (r[i] >= 0 && r[i] != c[i]) {
      int bin = r[i] >> 9;
      int slot = atomicAdd(&hist[bin], 1);
      if (slot < CAP)
        pairs[(size_t)bin * CAP + slot] =
            ((unsigned)(r[i] & 511) << 17) | (unsigned)c[i];
    }
  }
}

// ---------------------------------------------------------------------------
// K2: fine grouping within each coarse bucket (one block per bucket).
__global__ __launch_bounds__(256) void bucket_fine_kernel(
    const int* __restrict__ coarse_cursor, const unsigned* __restrict__ pairs,
    unsigned* __restrict__ colsp, int* __restrict__ count,
    int* __restrict__ row_start, float* __restrict__ dinv, int n_nodes) {
  __shared__ int hist[512];
  __shared__ int ssum[256];
  int tid = threadIdx.x;
  int b = blockIdx.x;
  size_t base = (size_t)b * CAP;
  int n_b = coarse_cursor[b];
  if (n_b > CAP) n_b = CAP;

  hist[tid] = 0;
  hist[tid + 256] = 0;
  __syncthreads();

  for (int i = tid; i < n_b; i += 256)
    atomicAdd(&hist[pairs[base + i] >> 17], 1);
  __syncthreads();

  int v0 = hist[2 * tid], v1 = hist[2 * tid + 1];
  ssum[tid] = v0 + v1;
  __syncthreads();
  for (int off = 1; off < 256; off <<= 1) {
    int t = (tid >= off) ? ssum[tid - off] : 0;
    __syncthreads();
    ssum[tid] += t;
    __syncthreads();
  }
  int e0 = (tid > 0) ? ssum[tid - 1] : 0;
  int e1 = e0 + v0;

  {
    int r0 = b * 512 + 2 * tid;
    if (r0 < n_nodes) {
      count[r0] = v0;
      row_start[r0] = (int)base + e0;
      dinv[r0] = rsqrtf((float)v0 + 1.0f);
    }
    int r1 = r0 + 1;
    if (r1 < n_nodes) {
      count[r1] = v1;
      row_start[r1] = (int)base + e1;
      dinv[r1] = rsqrtf((float)v1 + 1.0f);
    }
  }
  hist[2 * tid] = e0;
  hist[2 * tid + 1] = e1;
  __syncthreads();

  for (int i = tid; i < n_b; i += 256) {
    unsigned p = pairs[base + i];
    int slot = atomicAdd(&hist[p >> 17], 1);
    colsp[base + slot] = p & 0x1FFFFu;
  }
}

// ---------------------------------------------------------------------------
// Stage 4: xwd = dinv * (x @ W.T), output bf16 [N][64].
// No LDS round-trip for x: the B-fragment (node=lane&15, k=quad*8..+7) means
// each (node, 32-k chunk) is one aligned 128B line read fully by one quad
// column -> direct global->register loads, converted in-register. W (bf16,
// precomputed) staged once to padded LDS; one barrier per block, none in the
// k-loop.
#define WPAD 264  // 256+8 shorts: row stride 132 dwords -> low-order bank alias
__global__ __launch_bounds__(256) void matmul_kernel(
    const float* __restrict__ x, const unsigned short* __restrict__ Wb,
    const float* __restrict__ dinv, unsigned short* __restrict__ xwd,
    int n_nodes) {
  __shared__ unsigned short w_lds[64][WPAD];

  int tid = threadIdx.x;
  int wave = tid >> 6;
  int lane = tid & 63;
  int quad = lane >> 4;   // 0..3
  int lcol = lane & 15;   // 0..15
  long nbase = (long)blockIdx.x * 64;

  // --- stage Wb -> LDS (plain copy, no conversion): 4 threads per row.
  {
    int r = tid >> 2;
    int q = tid & 3;
    const unsigned short* src = Wb + (size_t)r * IN_SIZE + q * 64;
#pragma unroll
    for (int i = 0; i < 8; i++)
      *(short8*)(&w_lds[r][q * 64 + i * 8]) = *(const short8*)(src + i * 8);
  }
  __syncthreads();

  long node = nbase + wave * 16 + lcol;
  long nclamp = (node < (long)n_nodes) ? node : (long)(n_nodes - 1);
  const float* xrow = x + nclamp * IN_SIZE;

  floatx4 acc[4];
#pragma unroll
  for (int t = 0; t < 4; t++) acc[t] = (floatx4){0.f, 0.f, 0.f, 0.f};

#pragma unroll
  for (int kk = 0; kk < 8; kk++) {  // 8 K-steps of 32
    const float* p = xrow + kk * 32 + quad * 8;
    float4 a = *(const float4*)(p);
    float4 bb = *(const float4*)(p + 4);
    short8 bfrag;
    bfrag[0] = (short)f2bf(a.x);  bfrag[1] = (short)f2bf(a.y);
    bfrag[2] = (short)f2bf(a.z);  bfrag[3] = (short)f2bf(a.w);
    bfrag[4] = (short)f2bf(bb.x); bfrag[5] = (short)f2bf(bb.y);
    bfrag[6] = (short)f2bf(bb.z); bfrag[7] = (short)f2bf(bb.w);
#pragma unroll
    for (int t = 0; t < 4; t++) {
      short8 afrag = *(const short8*)(&w_lds[t * 16 + lcol][kk * 32 + quad * 8]);
      acc[t] =
          __builtin_amdgcn_mfma_f32_16x16x32_bf16(afrag, bfrag, acc[t], 0, 0, 0);
    }
  }

  // --- epilogue: D[m=ch][n=node]; lane: node = lcol, ch = quad*4+reg.
  if (node < (long)n_nodes) {
    float dv = dinv[node];
#pragma unroll
    for (int t = 0; t < 4; t++) {
      ushort4 sv;
      sv.x = f2bf(dv * acc[t][0]);
      sv.y = f2bf(dv * acc[t][1]);
      sv.z = f2bf(dv * acc[t][2]);
      sv.w = f2bf(dv * acc[t][3]);
      *(ushort4*)(xwd + node * OUT_SIZE + t * 16 + quad * 4) = sv;
    }
  }
}

// ---------------------------------------------------------------------------
// Stage 5: CSR gather. One wave per row; 8 edges per iteration.
// lane = cg(0..7: channel group of 8) x sub(0..7: edge slot).
// Each lane: short8 16B load = 8 ch of one edge -> one 1KB VMEM per 8 edges.
__global__ __launch_bounds__(256) void gather_kernel(
    const int* __restrict__ row_start, const int* __restrict__ count,
    const unsigned* __restrict__ colsp, const float* __restrict__ dinv,
    const unsigned short* __restrict__ xwd, float* __restrict__ out,
    int n_nodes) {
  int lane = threadIdx.x & 63;
  int r = blockIdx.x * 4 + (threadIdx.x >> 6);
  if (r >= n_nodes) return;
  int sub = lane & 7;   // edge slot 0..7
  int cg = lane >> 3;   // channels cg*8 .. cg*8+7
  int start = row_start[r];
  int cnt = count[r];

  float acc[8];
#pragma unroll
  for (int i = 0; i < 8; i++) acc[i] = 0.f;

  if (sub == 0) {  // self-loop term, once
    short8 v = *(const short8*)(xwd + (size_t)r * OUT_SIZE + cg * 8);
#pragma unroll
    for (int i = 0; i < 8; i++) acc[i] = bf2f((unsigned short)v[i]);
  }
  for (int j = 0; j < cnt; j += 8) {
    int idx = j + sub;
    bool act = idx < cnt;
    int c = act ? (int)colsp[start + idx] : r;  // dummy -> hot line, masked
    short8 v = *(const short8*)(xwd + (size_t)c * OUT_SIZE + cg * 8);
    float m = act ? 1.0f : 0.0f;
#pragma unroll
    for (int i = 0; i < 8; i++) acc[i] += m * bf2f((unsigned short)v[i]);
  }
  // butterfly-combine the 8 edge slots (sub = lane bits 0..2)
#pragma unroll
  for (int i = 0; i < 8; i++) {
    acc[i] += __shfl_xor(acc[i], 1);
    acc[i] += __shfl_xor(acc[i], 2);
    acc[i] += __shfl_xor(acc[i], 4);
  }

  if (sub == 0) {
    float dr = dinv[r];
    float4 o0 = make_float4(dr * acc[0], dr * acc[1], dr * acc[2], dr * acc[3]);
    float4 o1 = make_float4(dr * acc[4], dr * acc[5], dr * acc[6], dr * acc[7]);
    float* dst = out + (size_t)r * OUT_SIZE + cg * 8;
    *(float4*)(dst) = o0;
    *(float4*)(dst + 4) = o1;
  }
}

// ---------------------------------------------------------------------------
extern "C" void kernel_launch(void* const* d_in, const int* in_sizes, int n_in,
                              void* d_out, int out_size, void* d_ws,
                              size_t ws_size, hipStream_t stream) {
  const int* edge_index = (const int*)d_in[0];
  const float* x = (const float*)d_in[1];
  const float* W = (const float*)d_in[3];

  int n_edges = in_sizes[0] / 2;
  int n_nodes = in_sizes[1] / IN_SIZE;
  const int* row = edge_index;
  const int* col = edge_index + n_edges;
  float* out = (float*)d_out;

  int nbuck = (n_nodes + 511) >> 9;  // 196

  // Workspace: count[N] | row_start[N] | dinv[N] | coarse_cursor(4KB) |
  //            pairs[nbuck*CAP u32] | colsp[nbuck*CAP u32] |
  //            xwd[N*64 bf16] | Wb[64*256 bf16]
  char* ws = (char*)d_ws;
  size_t nb = ((size_t)n_nodes * 4 + 15) & ~(size_t)15;
  int* count = (int*)ws;
  int* row_start = (int*)(ws + nb);
  float* dinv = (float*)(ws + 2 * nb);
  int* coarse_cursor = (int*)(ws + 3 * nb);
  size_t bucketsB = (size_t)nbuck * CAP * 4;
  unsigned* pairs = (unsigned*)(ws + 3 * nb + 4096);
  unsigned* colsp = (unsigned*)(ws + 3 * nb + 4096 + bucketsB);
  unsigned short* xwd = (unsigned short*)(ws + 3 * nb + 4096 + 2 * bucketsB);
  unsigned short* Wb =
      (unsigned short*)(ws + 3 * nb + 4096 + 2 * bucketsB +
                        (size_t)n_nodes * OUT_SIZE * 2);

  hipMemsetAsync(coarse_cursor, 0, (size_t)nbuck * 4, stream);

  wconv_kernel<<<(OUT_SIZE * IN_SIZE + 255) / 256, 256, 0, stream>>>(
      W, Wb, OUT_SIZE * IN_SIZE);
  int nb1 = (n_edges + K1_TILE - 1) / K1_TILE;
  bucket_coarse_kernel<<<nb1, 256, 0, stream>>>(row, col, coarse_cursor,
                                                pairs, n_edges, nbuck);
  bucket_fine_kernel<<<nbuck, 256, 0, stream>>>(coarse_cursor, pairs, colsp,
                                                count, row_start, dinv,
                                                n_nodes);
  matmul_kernel<<<(n_nodes + 63) / 64, 256, 0, stream>>>(x, Wb, dinv, xwd,
                                                         n_nodes);
  gather_kernel<<<(n_nodes + 3) / 4, 256, 0, stream>>>(
      row_start, count, colsp, dinv, xwd, out, n_nodes);
}